// Round 1
// baseline (1122.653 us; speedup 1.0000x reference)
//
#include <hip/hip_runtime.h>

// HetConv fp32 baseline.
// out[n,i,y,x] = sum_{j%4==i%4} sum_{3x3} Wk[i,j,ky,kx] * xpad[n,j,y+ky-1,x+kx-1]
//             + sum_{j%4!=i%4} W1[i,j] * x[n,j,y,x]
//
// Grid: (16 spatial tiles, 4 residue groups g, 32 batch). Block 256 threads.
// Block computes the 64 output channels {g, g+4, ..., g+252} over a 16x16 tile.
// Input channels staged in LDS in chunks of 16; only the 4 chunk channels with
// ic%4==g take the 3x3 path, the other 12 take the 1x1 path.

#define IN_C  256
#define OUT_C 256
#define HH    64
#define WW    64
#define TH    16
#define TW    16
#define ICC   16

__global__ __launch_bounds__(256)
void hetconv_fp32(const float* __restrict__ x,
                  const float* __restrict__ Wk,
                  const float* __restrict__ W1,
                  float* __restrict__ out) {
    const int t    = threadIdx.x;
    const int g    = blockIdx.y;          // residue group 0..3
    const int n    = blockIdx.z;          // batch
    const int tile = blockIdx.x;          // 0..15
    const int ty0  = (tile >> 2) * TH;
    const int tx0  = (tile & 3) * TW;

    const int ol = t & 7;        // this thread's ocs: g + 4*(ol*8 + k), k=0..7
    const int pl = t >> 3;       // 0..31
    const int r  = pl >> 1;      // tile row 0..15
    const int ch = (pl & 1) * 8; // col half: 0 or 8 (8 contiguous pixels)

    // LDS: x tile [ic][18 rows][20 cols (pad for float4 alignment)]
    __shared__ __align__(16) float xs [ICC * 18 * 20];  // 23.0 KB
    __shared__ __align__(16) float w1s[ICC * 64];       //  4.0 KB  [ic][o]
    __shared__ __align__(16) float wks[4 * 9 * 64];     //  9.2 KB  [a][tap][o]

    float acc[8][8];
    #pragma unroll
    for (int k = 0; k < 8; ++k)
        #pragma unroll
        for (int p = 0; p < 8; ++p) acc[k][p] = 0.f;

    for (int ic0 = 0; ic0 < IN_C; ic0 += ICC) {
        // ---- stage x tile: ICC x 18x18 with zero halo ----
        for (int idx = t; idx < ICC * 18 * 18; idx += 256) {
            int ic  = idx / 324;
            int rem = idx - ic * 324;
            int rr  = rem / 18;
            int cc  = rem - rr * 18;
            int gy = ty0 + rr - 1, gx = tx0 + cc - 1;
            float v = 0.f;
            if (gy >= 0 && gy < HH && gx >= 0 && gx < WW)
                v = x[(((size_t)n * IN_C + ic0 + ic) * HH + gy) * WW + gx];
            xs[ic * 360 + rr * 20 + cc] = v;
        }
        // ---- stage W1 chunk: w1s[ic][o] = W1[g+4o][ic0+ic] ----
        for (int idx = t; idx < ICC * 64; idx += 256) {
            int ic = idx >> 6, o = idx & 63;
            w1s[idx] = W1[(g + 4 * o) * IN_C + ic0 + ic];
        }
        // ---- stage Wk chunk (active ics only): wks[a][tap][o] ----
        for (int idx = t; idx < 4 * 9 * 64; idx += 256) {
            int a   = idx / 576;
            int rem = idx - a * 576;
            int tap = rem >> 6, o = rem & 63;
            int oc = g + 4 * o;
            int ic = ic0 + g + 4 * a;
            wks[idx] = Wk[(oc * IN_C + ic) * 9 + tap];
        }
        __syncthreads();

        for (int ic = 0; ic < ICC; ++ic) {
            if ((ic & 3) != g) {
                // ---- 1x1 path (wave-uniform branch) ----
                const float* rowp = &xs[ic * 360 + (r + 1) * 20 + ch];
                float4 A = *(const float4*)rowp;        // rowp[0..3]
                float4 B = *(const float4*)(rowp + 4);  // rowp[4..7]
                float  c8 = rowp[8];
                float xv[8] = {A.y, A.z, A.w, B.x, B.y, B.z, B.w, c8}; // cols ch+1..ch+8
                const float* wp = &w1s[ic * 64 + ol * 8];
                float4 wA = *(const float4*)wp;
                float4 wB = *(const float4*)(wp + 4);
                float wv[8] = {wA.x, wA.y, wA.z, wA.w, wB.x, wB.y, wB.z, wB.w};
                #pragma unroll
                for (int k = 0; k < 8; ++k)
                    #pragma unroll
                    for (int p = 0; p < 8; ++p)
                        acc[k][p] += wv[k] * xv[p];
            } else {
                // ---- 3x3 path ----
                const int a = ic >> 2;
                #pragma unroll
                for (int dy = -1; dy <= 1; ++dy) {
                    const float* rowp = &xs[ic * 360 + (r + 1 + dy) * 20 + ch];
                    float4 A = *(const float4*)rowp;
                    float4 B = *(const float4*)(rowp + 4);
                    float2 C = *(const float2*)(rowp + 8);
                    float seg[10] = {A.x, A.y, A.z, A.w, B.x, B.y, B.z, B.w, C.x, C.y};
                    #pragma unroll
                    for (int dxi = 0; dxi < 3; ++dxi) {
                        const int tap = (dy + 1) * 3 + dxi;
                        const float* wp = &wks[(a * 9 + tap) * 64 + ol * 8];
                        float4 wA = *(const float4*)wp;
                        float4 wB = *(const float4*)(wp + 4);
                        float wv[8] = {wA.x, wA.y, wA.z, wA.w, wB.x, wB.y, wB.z, wB.w};
                        #pragma unroll
                        for (int k = 0; k < 8; ++k)
                            #pragma unroll
                            for (int p = 0; p < 8; ++p)
                                acc[k][p] += wv[k] * seg[p + dxi];
                    }
                }
            }
        }
        __syncthreads();
    }

    // ---- epilogue: 8 ocs x 8 contiguous pixels, float4 stores ----
    #pragma unroll
    for (int k = 0; k < 8; ++k) {
        int oc = g + 4 * (ol * 8 + k);
        size_t base = (((size_t)n * OUT_C + oc) * HH + (ty0 + r)) * WW + tx0 + ch;
        float4 v0 = {acc[k][0], acc[k][1], acc[k][2], acc[k][3]};
        float4 v1 = {acc[k][4], acc[k][5], acc[k][6], acc[k][7]};
        *(float4*)(&out[base])     = v0;
        *(float4*)(&out[base + 4]) = v1;
    }
}

extern "C" void kernel_launch(void* const* d_in, const int* in_sizes, int n_in,
                              void* d_out, int out_size, void* d_ws, size_t ws_size,
                              hipStream_t stream) {
    const float* x  = (const float*)d_in[0];
    const float* Wk = (const float*)d_in[1];
    const float* W1 = (const float*)d_in[2];
    float* out = (float*)d_out;

    dim3 grid(16, 4, 32);   // (spatial tiles, residue groups, batch)
    dim3 block(256);
    hetconv_fp32<<<grid, block, 0, stream>>>(x, Wk, W1, out);
}

// Round 2
// 105.140 us; speedup vs baseline: 10.6777x; 10.6777x over previous
//
#include <hip/hip_runtime.h>

// HetConv via bf16 MFMA implicit GEMM.
//   Part A: dense 256x256 pointwise GEMM with W_hat[oc,j] = (j%4==oc%4 ? Wk center : W1)
//   Part B: grouped (j%4==oc%4) 8 non-center taps, block-diagonal after group-major permute
// Channel permutation p = (c%4)*64 + c/4  <->  c = 4*(p&63) + (p>>6).
// Prepass writes bf16 weights to d_ws in LDS-image layout (rows padded to 40 elems = 80B = 5*16B
// so b128 fragment reads are bank-conflict-free without XOR swizzle).

#define IN_C  256
#define OUT_C 256
#define HH    64
#define WW    64

typedef __attribute__((ext_vector_type(8))) short   bf16x8;
typedef __attribute__((ext_vector_type(4))) float   f32x4;

__device__ __forceinline__ unsigned short f2bf(float f) {
    union { float f; unsigned int u; } v; v.f = f;
    unsigned int r = (v.u + 0x7FFFu + ((v.u >> 16) & 1u)) >> 16;
    return (unsigned short)r;
}

// ---------------- weight prepass ----------------
// ws16 layout (elems, bf16):
//   What: [h=0..7][p=0..255][40]            (h = h2*4+g ; j = g + 4*(32*h2 + i))
//   Wkt : offset 81920: [h][tap=0..7][lo=0..63][40]   (tap_full = tap<4 ? tap : tap+1)
__global__ __launch_bounds__(256)
void hetconv_prep(const float* __restrict__ Wk, const float* __restrict__ W1,
                  unsigned short* __restrict__ ws16) {
    const int total = 81920 + 163840;
    for (int idx = blockIdx.x * 256 + threadIdx.x; idx < total; idx += gridDim.x * 256) {
        float f = 0.f;
        if (idx < 81920) {
            int i = idx % 40;
            int p = (idx / 40) & 255;
            int h = idx / 10240;
            int g = h & 3, h2 = h >> 2;
            if (i < 32) {
                int j  = g + 4 * (32 * h2 + i);
                int oc = 4 * (p & 63) + (p >> 6);
                f = ((p >> 6) == g) ? Wk[(oc * IN_C + j) * 9 + 4] : W1[oc * IN_C + j];
            }
        } else {
            int widx = idx - 81920;
            int i   = widx % 40;
            int lo  = (widx / 40) & 63;
            int tap = (widx / 2560) & 7;
            int h   = widx / 20480;
            int g = h & 3, h2 = h >> 2;
            if (i < 32) {
                int j  = g + 4 * (32 * h2 + i);
                int oc = 4 * lo + g;
                int tf = tap < 4 ? tap : tap + 1;
                f = Wk[(oc * IN_C + j) * 9 + tf];
            }
        }
        ws16[idx] = f2bf(f);
    }
}

// ---------------- main MFMA kernel ----------------
// Block: 256 thr (4 waves, 2 Mrows x 2 Ncols). Computes all 256 oc x 128 px
// (2 output rows x 64 cols) for one (n, ytile). K-loop: 8 chunks of 32 ic
// (chunk = (h2, g): j = g + 4*(32*h2 + i)).
__global__ __launch_bounds__(256, 2)
void hetconv_mfma(const float* __restrict__ x,
                  const unsigned short* __restrict__ wsw,
                  float* __restrict__ out) {
    __shared__ unsigned short xs[4 * 66 * 40];   // 21120 B  [r][c(-1..64 ->0..65)][ic pad40]
    __shared__ unsigned short wh[256 * 40];      // 20480 B  W_hat chunk [p][i pad40]
    __shared__ unsigned short wk[4 * 64 * 40];   // 20480 B  4 taps [tap][lo][i pad40]

    const int t    = threadIdx.x;
    const int l    = t & 63;
    const int w    = t >> 6;
    const int mrow = w & 1;       // M half: owns M-tiles m = mrow + 2*mi
    const int ncol = w >> 1;      // N half: output row ysub = ncol, cols ni*16+lrow
    const int lrow = l & 15;      // a-row / b-col / c-col within 16
    const int kc   = l >> 4;      // k-chunk 0..3 (8 elems each)

    // XCD-aware decode: xcd = bid&7 gets n in [4*xcd, 4*xcd+4), sequential ytiles
    const int bid = blockIdx.x;
    const int n   = (bid & 7) * 4 + (bid >> 8);
    const int yt  = (bid >> 3) & 31;
    const int y0  = yt * 2;

    f32x4 acc[8][4];
    #pragma unroll
    for (int mi = 0; mi < 8; ++mi)
        #pragma unroll
        for (int ni = 0; ni < 4; ++ni) acc[mi][ni] = (f32x4){0.f, 0.f, 0.f, 0.f};

    // zero halo cols (c=0 and c=65) once; main staging never touches them
    if (t < 128) {
        int r = t >> 5, side = (t >> 4) & 1, icp = t & 15;
        *(unsigned int*)&xs[(r * 66 + side * 65) * 40 + icp * 2] = 0u;
    }

    for (int h2 = 0; h2 < 2; ++h2) {
        #pragma unroll
        for (int g = 0; g < 4; ++g) {
            const int h = h2 * 4 + g;
            __syncthreads();   // previous chunk fully consumed

            // ---- stage x chunk: 32 ic x 4 rows x 64 cols, fp32->bf16, transpose to ic-innermost ----
            // tasks: [r(4)][q(16 col-quads)][icp(16 ic-pairs)], icp fastest -> 2-way max write conflicts
            #pragma unroll
            for (int it = 0; it < 4; ++it) {
                int tau = t + it * 256;
                int icp = tau & 15;
                int q   = (tau >> 4) & 15;
                int r   = tau >> 8;
                int i0  = icp * 2;
                int j0  = g + 4 * (32 * h2 + i0);
                int gy  = y0 + r - 1;
                float4 v0 = {0.f, 0.f, 0.f, 0.f}, v1 = {0.f, 0.f, 0.f, 0.f};
                if ((unsigned)gy < 64u) {
                    const float* p0 = x + (((size_t)n * IN_C + j0) << 12) + (gy << 6) + q * 4;
                    v0 = *(const float4*)p0;
                    v1 = *(const float4*)(p0 + 4 * HH * WW);   // plane j0+4
                }
                unsigned int d0 = (unsigned)f2bf(v0.x) | ((unsigned)f2bf(v1.x) << 16);
                unsigned int d1 = (unsigned)f2bf(v0.y) | ((unsigned)f2bf(v1.y) << 16);
                unsigned int d2 = (unsigned)f2bf(v0.z) | ((unsigned)f2bf(v1.z) << 16);
                unsigned int d3 = (unsigned)f2bf(v0.w) | ((unsigned)f2bf(v1.w) << 16);
                int rb = (r * 66 + q * 4 + 1) * 40 + i0;
                *(unsigned int*)&xs[rb]           = d0;
                *(unsigned int*)&xs[rb + 40]      = d1;
                *(unsigned int*)&xs[rb + 80]      = d2;
                *(unsigned int*)&xs[rb + 120]     = d3;
            }
            // ---- stage W_hat chunk + wk taps 0-3 (straight 16B copies) ----
            {
                const unsigned short* hs = wsw + h * 10240;
                const unsigned short* ks = wsw + 81920 + h * 20480;
                #pragma unroll
                for (int it = 0; it < 5; ++it) {
                    int e = (t + it * 256) * 8;
                    *(bf16x8*)&wh[e] = *(const bf16x8*)&hs[e];
                    *(bf16x8*)&wk[e] = *(const bf16x8*)&ks[e];
                }
            }
            __syncthreads();

            // ---- part A: dense pointwise, K=32 (1 MFMA per C-tile) ----
            {
                bf16x8 a[8], b[4];
                #pragma unroll
                for (int mi = 0; mi < 8; ++mi) {
                    int m = mrow + 2 * mi;
                    a[mi] = *(const bf16x8*)&wh[(m * 16 + lrow) * 40 + kc * 8];
                }
                #pragma unroll
                for (int ni = 0; ni < 4; ++ni)
                    b[ni] = *(const bf16x8*)&xs[((ncol + 1) * 66 + ni * 16 + lrow + 1) * 40 + kc * 8];
                #pragma unroll
                for (int mi = 0; mi < 8; ++mi)
                    #pragma unroll
                    for (int ni = 0; ni < 4; ++ni)
                        acc[mi][ni] = __builtin_amdgcn_mfma_f32_16x16x32_bf16(a[mi], b[ni], acc[mi][ni], 0, 0, 0);
            }

            // ---- part B taps 0-3 (tap_full = 0..3) ----
            #pragma unroll
            for (int tp = 0; tp < 4; ++tp) {
                const int tf = tp;
                const int dy = tf / 3 - 1, dx = tf % 3 - 1;
                bf16x8 a0 = *(const bf16x8*)&wk[(tp * 64 + mrow * 16 + lrow) * 40 + kc * 8];
                bf16x8 a1 = *(const bf16x8*)&wk[(tp * 64 + (mrow + 2) * 16 + lrow) * 40 + kc * 8];
                bf16x8 bb[4];
                #pragma unroll
                for (int ni = 0; ni < 4; ++ni)
                    bb[ni] = *(const bf16x8*)&xs[((ncol + 1 + dy) * 66 + ni * 16 + lrow + 1 + dx) * 40 + kc * 8];
                #pragma unroll
                for (int ni = 0; ni < 4; ++ni) {
                    acc[2 * g + 0][ni] = __builtin_amdgcn_mfma_f32_16x16x32_bf16(a0, bb[ni], acc[2 * g + 0][ni], 0, 0, 0);
                    acc[2 * g + 1][ni] = __builtin_amdgcn_mfma_f32_16x16x32_bf16(a1, bb[ni], acc[2 * g + 1][ni], 0, 0, 0);
                }
            }
            __syncthreads();

            // ---- stage wk taps 4-7 (tap_full = 5..8) ----
            {
                const unsigned short* ks = wsw + 81920 + h * 20480 + 10240;
                #pragma unroll
                for (int it = 0; it < 5; ++it) {
                    int e = (t + it * 256) * 8;
                    *(bf16x8*)&wk[e] = *(const bf16x8*)&ks[e];
                }
            }
            __syncthreads();

            // ---- part B taps 4-7 ----
            #pragma unroll
            for (int tp = 0; tp < 4; ++tp) {
                const int tf = tp + 5;
                const int dy = tf / 3 - 1, dx = tf % 3 - 1;
                bf16x8 a0 = *(const bf16x8*)&wk[(tp * 64 + mrow * 16 + lrow) * 40 + kc * 8];
                bf16x8 a1 = *(const bf16x8*)&wk[(tp * 64 + (mrow + 2) * 16 + lrow) * 40 + kc * 8];
                bf16x8 bb[4];
                #pragma unroll
                for (int ni = 0; ni < 4; ++ni)
                    bb[ni] = *(const bf16x8*)&xs[((ncol + 1 + dy) * 66 + ni * 16 + lrow + 1 + dx) * 40 + kc * 8];
                #pragma unroll
                for (int ni = 0; ni < 4; ++ni) {
                    acc[2 * g + 0][ni] = __builtin_amdgcn_mfma_f32_16x16x32_bf16(a0, bb[ni], acc[2 * g + 0][ni], 0, 0, 0);
                    acc[2 * g + 1][ni] = __builtin_amdgcn_mfma_f32_16x16x32_bf16(a1, bb[ni], acc[2 * g + 1][ni], 0, 0, 0);
                }
            }
        }
    }

    // ---- epilogue: C/D layout col=lane&15, row=(lane>>4)*4+reg ----
    #pragma unroll
    for (int mi = 0; mi < 8; ++mi) {
        int m = mrow + 2 * mi;
        #pragma unroll
        for (int ni = 0; ni < 4; ++ni) {
            #pragma unroll
            for (int reg = 0; reg < 4; ++reg) {
                int p  = m * 16 + kc * 4 + reg;
                int oc = 4 * (p & 63) + (p >> 6);
                out[(((size_t)n * OUT_C + oc) * HH + (y0 + ncol)) * WW + ni * 16 + lrow] = acc[mi][ni][reg];
            }
        }
    }
}

// ---------------- fp32 fallback (round-1 kernel, used only if ws too small) ----------------
#define TH 16
#define TW 16
#define ICC 16
__global__ __launch_bounds__(256)
void hetconv_fp32(const float* __restrict__ x,
                  const float* __restrict__ Wk,
                  const float* __restrict__ W1,
                  float* __restrict__ out) {
    const int t    = threadIdx.x;
    const int g    = blockIdx.y;
    const int n    = blockIdx.z;
    const int tile = blockIdx.x;
    const int ty0  = (tile >> 2) * TH;
    const int tx0  = (tile & 3) * TW;
    const int ol = t & 7;
    const int pl = t >> 3;
    const int r  = pl >> 1;
    const int ch = (pl & 1) * 8;
    __shared__ __align__(16) float xsf[ICC * 18 * 20];
    __shared__ __align__(16) float w1s[ICC * 64];
    __shared__ __align__(16) float wks[4 * 9 * 64];
    float acc[8][8];
    #pragma unroll
    for (int k = 0; k < 8; ++k)
        #pragma unroll
        for (int p = 0; p < 8; ++p) acc[k][p] = 0.f;
    for (int ic0 = 0; ic0 < IN_C; ic0 += ICC) {
        for (int idx = t; idx < ICC * 18 * 18; idx += 256) {
            int ic = idx / 324, rem = idx - ic * 324, rr = rem / 18, cc = rem - rr * 18;
            int gy = ty0 + rr - 1, gx = tx0 + cc - 1;
            float v = 0.f;
            if (gy >= 0 && gy < HH && gx >= 0 && gx < WW)
                v = x[(((size_t)n * IN_C + ic0 + ic) * HH + gy) * WW + gx];
            xsf[ic * 360 + rr * 20 + cc] = v;
        }
        for (int idx = t; idx < ICC * 64; idx += 256) {
            int ic = idx >> 6, o = idx & 63;
            w1s[idx] = W1[(g + 4 * o) * IN_C + ic0 + ic];
        }
        for (int idx = t; idx < 4 * 9 * 64; idx += 256) {
            int a = idx / 576, rem = idx - a * 576, tap = rem >> 6, o = rem & 63;
            wks[idx] = Wk[((g + 4 * o) * IN_C + ic0 + g + 4 * a) * 9 + tap];
        }
        __syncthreads();
        for (int ic = 0; ic < ICC; ++ic) {
            if ((ic & 3) != g) {
                const float* rowp = &xsf[ic * 360 + (r + 1) * 20 + ch];
                float4 A = *(const float4*)rowp;
                float4 B = *(const float4*)(rowp + 4);
                float  c8 = rowp[8];
                float xv[8] = {A.y, A.z, A.w, B.x, B.y, B.z, B.w, c8};
                const float* wp = &w1s[ic * 64 + ol * 8];
                float4 wA = *(const float4*)wp;
                float4 wB = *(const float4*)(wp + 4);
                float wv[8] = {wA.x, wA.y, wA.z, wA.w, wB.x, wB.y, wB.z, wB.w};
                #pragma unroll
                for (int k = 0; k < 8; ++k)
                    #pragma unroll
                    for (int p = 0; p < 8; ++p) acc[k][p] += wv[k] * xv[p];
            } else {
                const int a = ic >> 2;
                #pragma unroll
                for (int dy = -1; dy <= 1; ++dy) {
                    const float* rowp = &xsf[ic * 360 + (r + 1 + dy) * 20 + ch];
                    float4 A = *(const float4*)rowp;
                    float4 B = *(const float4*)(rowp + 4);
                    float2 C = *(const float2*)(rowp + 8);
                    float seg[10] = {A.x, A.y, A.z, A.w, B.x, B.y, B.z, B.w, C.x, C.y};
                    #pragma unroll
                    for (int dxi = 0; dxi < 3; ++dxi) {
                        const float* wp = &wks[(a * 9 + (dy + 1) * 3 + dxi) * 64 + ol * 8];
                        float4 wA = *(const float4*)wp;
                        float4 wB = *(const float4*)(wp + 4);
                        float wv[8] = {wA.x, wA.y, wA.z, wA.w, wB.x, wB.y, wB.z, wB.w};
                        #pragma unroll
                        for (int k = 0; k < 8; ++k)
                            #pragma unroll
                            for (int p = 0; p < 8; ++p) acc[k][p] += wv[k] * seg[p + dxi];
                    }
                }
            }
        }
        __syncthreads();
    }
    #pragma unroll
    for (int k = 0; k < 8; ++k) {
        int oc = g + 4 * (ol * 8 + k);
        size_t base = (((size_t)n * OUT_C + oc) * HH + (ty0 + r)) * WW + tx0 + ch;
        float4 v0 = {acc[k][0], acc[k][1], acc[k][2], acc[k][3]};
        float4 v1 = {acc[k][4], acc[k][5], acc[k][6], acc[k][7]};
        *(float4*)(&out[base])     = v0;
        *(float4*)(&out[base + 4]) = v1;
    }
}

extern "C" void kernel_launch(void* const* d_in, const int* in_sizes, int n_in,
                              void* d_out, int out_size, void* d_ws, size_t ws_size,
                              hipStream_t stream) {
    const float* x  = (const float*)d_in[0];
    const float* Wk = (const float*)d_in[1];
    const float* W1 = (const float*)d_in[2];
    float* outp = (float*)d_out;

    if (ws_size >= (size_t)(81920 + 163840) * sizeof(unsigned short)) {
        hetconv_prep<<<240, 256, 0, stream>>>(Wk, W1, (unsigned short*)d_ws);
        hetconv_mfma<<<1024, 256, 0, stream>>>(x, (const unsigned short*)d_ws, outp);
    } else {
        hetconv_fp32<<<dim3(16, 4, 32), 256, 0, stream>>>(x, Wk, W1, outp);
    }
}